// Round 5
// baseline (236.090 us; speedup 1.0000x reference)
//
#include <hip/hip_runtime.h>

typedef unsigned short u16;
typedef unsigned int   u32;
typedef __attribute__((ext_vector_type(8))) short short8;
typedef __attribute__((ext_vector_type(4))) float f32x4;

#define AS1 __attribute__((address_space(1)))
#define AS3 __attribute__((address_space(3)))

#define NSEQ  1025
#define BB    8
#define DD    768
#define HH    12
#define MROWS 8200   // B*N valid rows
#define MPAD  8320   // padded to 65*128
#define KPAD  1088   // keys padded to 17*64

__device__ __forceinline__ void gl2lds16(const void* g, void* l) {
  __builtin_amdgcn_global_load_lds((const AS1 u32*)g, (AS3 u32*)l, 16, 0, 0);
}
__device__ __forceinline__ u16 f2bf(float f) {
  u32 u = __float_as_uint(f);
  return (u16)((u + 0x7FFFu + ((u >> 16) & 1u)) >> 16);
}
__device__ __forceinline__ float bf2f(u16 u) { return __uint_as_float(((u32)u) << 16); }

// ---------------------------------------------------------------------------
// prep (+fused q0): blocks < 7968: cast x -> xb bf16 [MPAD x 768] (transposed
// (n,b)->(b,n)), w_qkv rows [768,2304) -> wkv, w_proj -> wpj.
// blocks >= 7968 (96 of them): q0[b,d'] = sum_e x[0,b,e]*w_qkv[d',e] (fp32).
// ---------------------------------------------------------------------------
__global__ __launch_bounds__(256) void prep(const float* __restrict__ x,
                                            const float* __restrict__ wqkv,
                                            const float* __restrict__ wproj,
                                            u16* __restrict__ xb,
                                            u16* __restrict__ wkv,
                                            u16* __restrict__ wpj,
                                            float* __restrict__ q0) {
  __shared__ float red[256];
  const int XB_G  = MPAD * 192;   // float4 groups
  const int WKV_G = 1536 * 192;
  const int WPJ_G = 768 * 192;
  int tid = threadIdx.x;
  if (blockIdx.x >= 7968) {       // ---- q0 path ----
    int bid = blockIdx.x - 7968;
    int b = bid / HH, c = bid - b * HH;
    int dp = (c << 6) + (tid >> 2), part = tid & 3;
    const float4* x4 = (const float4*)(x + (size_t)b * DD + part * 192);
    const float4* w4 = (const float4*)(wqkv + (size_t)dp * DD + part * 192);
    float acc = 0.f;
#pragma unroll 4
    for (int e = 0; e < 48; ++e) {
      float4 a = x4[e], w = w4[e];
      acc += a.x * w.x + a.y * w.y + a.z * w.z + a.w * w.w;
    }
    red[tid] = acc;
    __syncthreads();
    if (part == 0) q0[b * DD + dp] = red[tid] + red[tid + 1] + red[tid + 2] + red[tid + 3];
    return;
  }
  int g = blockIdx.x * 256 + tid;
  float4 v;
  u16* dst;
  size_t di;
  if (g < XB_G) {
    int m = g / 192, e4 = g - m * 192;
    if (m < MROWS) {
      int bb = m / NSEQ, ns = m - bb * NSEQ;
      v = ((const float4*)x)[(size_t)(ns * BB + bb) * 192 + e4];
    } else {
      v.x = v.y = v.z = v.w = 0.f;
    }
    dst = xb; di = (size_t)g;
  } else if (g < XB_G + WKV_G) {
    int r = g - XB_G;
    v = ((const float4*)wqkv)[(size_t)147456 + r];  // skip first 768 rows
    dst = wkv; di = (size_t)r;
  } else {
    int r = g - XB_G - WKV_G;
    v = ((const float4*)wproj)[r];
    dst = wpj; di = (size_t)r;
  }
  uint2 o;
  o.x = (u32)f2bf(v.x) | ((u32)f2bf(v.y) << 16);
  o.y = (u32)f2bf(v.z) | ((u32)f2bf(v.w) << 16);
  ((uint2*)dst)[di] = o;
}

// ---------------------------------------------------------------------------
// gemm_bt: C[m,n] = sum_k A[m,k]*W[n,k]; 128x128 tile, BK=64 (12 iters of 32
// MFMA -> half the barrier drains vs BK=32). XCD-aware 1D grid: id&7 owns
// m-tiles {r, r+8, ...} so same-XCD blocks share A-tiles; W stays L2-resident.
// NT = n-tiles. MODE 0: bf16 store. MODE 1: +bias, fp32 scatter to [N,B,D].
// ---------------------------------------------------------------------------
template <int MODE, int NT>
__global__ __launch_bounds__(256) void gemm_bt(const u16* __restrict__ A,
                                               const u16* __restrict__ W,
                                               u16* __restrict__ Cbf,
                                               float* __restrict__ Cf,
                                               const float* __restrict__ bias,
                                               int ldc) {
  __shared__ u16 sA[128 * 64];
  __shared__ u16 sW[128 * 64];
  const int id = blockIdx.x;
  const int rx = id & 7, qx = id >> 3;
  const int kq = qx / NT;
  const int m_t = rx + (kq << 3);
  if (m_t > 64) return;
  const int n_t = qx - kq * NT;
  const int m0 = m_t << 7, n0 = n_t << 7;

  const int tid = threadIdx.x;
  const int w = tid >> 6, lane = tid & 63;
  const int wm = w & 1, wn = w >> 1;
  const int lc = lane & 15, lr = lane >> 4;

  f32x4 zero4 = {0.f, 0.f, 0.f, 0.f};
  f32x4 acc[4][4];
#pragma unroll
  for (int i = 0; i < 4; ++i)
#pragma unroll
    for (int j = 0; j < 4; ++j) acc[i][j] = zero4;

  const int r0 = tid >> 3;        // staging row 0..31 (+32 per chunk j)
  const int ko = (tid & 7) << 3;  // k-offset in elements
  const u16* gA = A + (size_t)(m0 + r0) * DD + ko;
  const u16* gW = W + (size_t)(n0 + r0) * DD + ko;
  char* lA = (char*)sA + tid * 16;
  char* lW = (char*)sW + tid * 16;

#pragma unroll 1
  for (int kt = 0; kt < 12; ++kt) {
    __syncthreads();
#pragma unroll
    for (int j = 0; j < 4; ++j) {
      gl2lds16(gA + (size_t)j * 32 * DD + kt * 64, lA + j * 4096);
      gl2lds16(gW + (size_t)j * 32 * DD + kt * 64, lW + j * 4096);
    }
    __syncthreads();
#pragma unroll
    for (int kk = 0; kk < 2; ++kk) {
      short8 af[4], wf[4];
#pragma unroll
      for (int mt = 0; mt < 4; ++mt)
        af[mt] = *(const short8*)((char*)sA + ((wm << 6) + (mt << 4) + lc) * 128 + (kk << 6) + (lr << 4));
#pragma unroll
      for (int nt = 0; nt < 4; ++nt)
        wf[nt] = *(const short8*)((char*)sW + ((wn << 6) + (nt << 4) + lc) * 128 + (kk << 6) + (lr << 4));
#pragma unroll
      for (int mt = 0; mt < 4; ++mt)
#pragma unroll
        for (int nt = 0; nt < 4; ++nt)
          acc[mt][nt] = __builtin_amdgcn_mfma_f32_16x16x32_bf16(af[mt], wf[nt], acc[mt][nt], 0, 0, 0);
    }
  }

  if (MODE == 0) {
#pragma unroll
    for (int mt = 0; mt < 4; ++mt)
#pragma unroll
      for (int r = 0; r < 4; ++r) {
        int m = m0 + (wm << 6) + (mt << 4) + (lr << 2) + r;
        if (m < MROWS) {
          size_t base = (size_t)m * ldc + n0 + (wn << 6) + lc;
#pragma unroll
          for (int nt = 0; nt < 4; ++nt) Cbf[base + (nt << 4)] = f2bf(acc[mt][nt][r]);
        }
      }
  } else {
    float b4[4];
#pragma unroll
    for (int nt = 0; nt < 4; ++nt) b4[nt] = bias[n0 + (wn << 6) + (nt << 4) + lc];
#pragma unroll
    for (int mt = 0; mt < 4; ++mt)
#pragma unroll
      for (int r = 0; r < 4; ++r) {
        int m = m0 + (wm << 6) + (mt << 4) + (lr << 2) + r;
        if (m < MROWS) {
          int bb = m / NSEQ;
          int ns = m - bb * NSEQ;
          float* o = Cf + (size_t)ns * (BB * DD) + bb * DD + n0 + (wn << 6) + lc;
#pragma unroll
          for (int nt = 0; nt < 4; ++nt) o[nt << 4] = acc[mt][nt][r] + b4[nt];
        }
      }
  }
}

// ---------------------------------------------------------------------------
// transpose_v: vT[bh][d][key] raw (KPAD cols, zero-padded) AND
//              vn[bh][key][64] = v/max(||v||,eps) bf16 (zero pad rows)
// ---------------------------------------------------------------------------
__global__ __launch_bounds__(256) void transpose_v(const u16* __restrict__ kv,
                                                   u16* __restrict__ vT,
                                                   u16* __restrict__ vn) {
  __shared__ u16 tile[64][72];
  __shared__ float red[256];
  __shared__ float sInv[64];
  int bid = blockIdx.x;
  int kc = bid % 17;
  int t2 = bid / 17;
  int h = t2 % HH, b = t2 / HH;
  int tid = threadIdx.x;
  int kl = tid >> 2, dc = (tid & 3) << 4;
  int key = kc * 64 + kl;
  u32 vals[8];
  if (key < NSEQ) {
    const u32* g = (const u32*)(kv + ((size_t)b * NSEQ + key) * 1536 + DD + h * 64 + dc);
#pragma unroll
    for (int i = 0; i < 8; ++i) vals[i] = g[i];
  } else {
#pragma unroll
    for (int i = 0; i < 8; ++i) vals[i] = 0;
  }
  float part = 0.f;
#pragma unroll
  for (int i = 0; i < 8; ++i) {
    float a = bf2f((u16)(vals[i] & 0xFFFF));
    float c = bf2f((u16)(vals[i] >> 16));
    part += a * a + c * c;
    ((u32*)&tile[kl][dc])[i] = vals[i];
  }
  red[tid] = part;
  __syncthreads();
  if ((tid & 3) == 0) {
    float s = red[tid] + red[tid + 1] + red[tid + 2] + red[tid + 3];
    sInv[kl] = (key < NSEQ) ? 1.0f / fmaxf(sqrtf(s), 1e-6f) : 0.0f;
  }
  __syncthreads();
  // normalized bf16 rows -> vn
  float iv = sInv[kl];
  u32 ovn[8];
#pragma unroll
  for (int i = 0; i < 8; ++i) {
    float a = bf2f((u16)(vals[i] & 0xFFFF)) * iv;
    float c = bf2f((u16)(vals[i] >> 16)) * iv;
    ovn[i] = (u32)f2bf(a) | ((u32)f2bf(c) << 16);
  }
  u32* on = (u32*)(vn + ((size_t)(b * HH + h) * KPAD + key) * 64 + dc);
#pragma unroll
  for (int i = 0; i < 8; ++i) on[i] = ovn[i];
  // raw transpose -> vT
  int dl = tid >> 2, ks = (tid & 3) << 4;
  u32 ov[8];
#pragma unroll
  for (int i = 0; i < 8; ++i)
    ov[i] = (u32)tile[ks + 2 * i][dl] | ((u32)tile[ks + 2 * i + 1][dl] << 16);
  u16* o = vT + (size_t)(b * HH + h) * 64 * KPAD + (size_t)dl * KPAD + kc * 64 + ks;
#pragma unroll
  for (int i = 0; i < 8; ++i) ((u32*)o)[i] = ov[i];
}

// ---------------------------------------------------------------------------
// vv_attn (+fused row0): grid (96, 9). y<8: per (bh, 128-q-tile):
// S^T = Kn·Qn^T (MFMA); p = 1 + 0.125c + 0.0078125c^2 (2 FMA — quadratic
// Taylor of e^{0.125c}, |c|<=1, rel err 3.3e-4 << bf16 quant); truncate-pack
// to bf16 via v_perm (no round add — one-sided err cancels in num/den);
// P->LDS; out += P@V^T; den += P@ones. y==8: row-0 fp32 attention per bh.
// Grid x=bh so same-bh q-tiles share an XCD -> K/V L2-resident.
// ---------------------------------------------------------------------------
__global__ __launch_bounds__(256) void vv_attn(const u16* __restrict__ vn,
                                               const u16* __restrict__ vT,
                                               u16* __restrict__ attn,
                                               const float* __restrict__ q0,
                                               const u16* __restrict__ kv) {
  __shared__ __align__(16) char smem[51200];
  const int tid = threadIdx.x;
  const int bh = blockIdx.x;  // 0..95
  const int b = bh / HH, h = bh - b * HH;

  if (blockIdx.y == 8) {  // ---- row0 path ----
    float* sq  = (float*)smem;            // 64
    float* sc  = (float*)(smem + 256);    // 1025
    float* red = (float*)(smem + 4608);   // 256
    float (*rpv)[68] = (float(*)[68])(smem + 5632);  // 32 x 68
    if (tid < 64) sq[tid] = q0[b * DD + h * 64 + tid];
    __syncthreads();
    float mx = -1e30f;
    for (int n = tid; n < NSEQ; n += 256) {
      const u32* kr = (const u32*)(kv + ((size_t)b * NSEQ + n) * 1536 + h * 64);
      float s = 0.f;
#pragma unroll
      for (int i = 0; i < 32; ++i) {
        u32 u = kr[i];
        s += bf2f((u16)(u & 0xFFFF)) * sq[2 * i] + bf2f((u16)(u >> 16)) * sq[2 * i + 1];
      }
      s *= 0.125f;
      sc[n] = s;
      mx = fmaxf(mx, s);
    }
    red[tid] = mx;
    __syncthreads();
    for (int st = 128; st > 0; st >>= 1) {
      if (tid < st) red[tid] = fmaxf(red[tid], red[tid + st]);
      __syncthreads();
    }
    mx = red[0];
    __syncthreads();
    float ds = 0.f;
    for (int n = tid; n < NSEQ; n += 256) {
      float p = __expf(sc[n] - mx);
      sc[n] = p;
      ds += p;
    }
    red[tid] = ds;
    __syncthreads();
    for (int st = 128; st > 0; st >>= 1) {
      if (tid < st) red[tid] += red[tid + st];
      __syncthreads();
    }
    float den = red[0];
    __syncthreads();
    int kp = tid >> 3, dc = (tid & 7) << 3;
    const u16* vb = kv + (size_t)b * NSEQ * 1536 + DD + h * 64 + dc;
    float acc[8];
#pragma unroll
    for (int i = 0; i < 8; ++i) acc[i] = 0.f;
#pragma unroll 4
    for (int j = 0; j < 32; ++j) {
      int n = kp + (j << 5);
      uint4 v = *(const uint4*)(vb + (size_t)n * 1536);
      float p = sc[n];
      acc[0] += p * bf2f((u16)(v.x & 0xFFFF));
      acc[1] += p * bf2f((u16)(v.x >> 16));
      acc[2] += p * bf2f((u16)(v.y & 0xFFFF));
      acc[3] += p * bf2f((u16)(v.y >> 16));
      acc[4] += p * bf2f((u16)(v.z & 0xFFFF));
      acc[5] += p * bf2f((u16)(v.z >> 16));
      acc[6] += p * bf2f((u16)(v.w & 0xFFFF));
      acc[7] += p * bf2f((u16)(v.w >> 16));
    }
    if (kp == 0) {  // key 1024
      uint4 v = *(const uint4*)(vb + (size_t)1024 * 1536);
      float p = sc[1024];
      acc[0] += p * bf2f((u16)(v.x & 0xFFFF));
      acc[1] += p * bf2f((u16)(v.x >> 16));
      acc[2] += p * bf2f((u16)(v.y & 0xFFFF));
      acc[3] += p * bf2f((u16)(v.y >> 16));
      acc[4] += p * bf2f((u16)(v.z & 0xFFFF));
      acc[5] += p * bf2f((u16)(v.z >> 16));
      acc[6] += p * bf2f((u16)(v.w & 0xFFFF));
      acc[7] += p * bf2f((u16)(v.w >> 16));
    }
#pragma unroll
    for (int i = 0; i < 8; ++i) rpv[kp][dc + i] = acc[i];
    __syncthreads();
    if (tid < 64) {
      float s = 0.f;
#pragma unroll
      for (int p = 0; p < 32; ++p) s += rpv[p][tid];
      attn[(size_t)b * NSEQ * DD + h * 64 + tid] = f2bf(s / den);
    }
    return;
  }

  // ---- VV path ----
  char* cQ = smem;           // [d-half][qrow 128][k 32]  16384 B
  char* cK = smem + 16384;   // [d-half][keyrow 64][k 32]  8192 B
  char* cV = smem + 24576;   // [key-half][d 64][k 32]     8192 B
  char* cP = smem + 32768;   // [q][key 64 (+8 pad)] 144B stride, 18432 B

  const int w = tid >> 6, lane = tid & 63;
  const int lc = lane & 15, lr = lane >> 4;
  const int m0 = blockIdx.y << 7;
  const char* nb = (const char*)(vn + (size_t)bh * KPAD * 64);  // 128B rows
  const char* tb = (const char*)(vT + (size_t)bh * 64 * KPAD);  // 2176B rows

  // stage Q tile (vn rows 1+m0 .. 1+m0+127), once; LDS layout [hf][row][32]
#pragma unroll
  for (int j = 0; j < 4; ++j) {
    int lin = (w << 12) + (j << 10) + (lane << 4);
    int hf = lin >> 13, r = (lin >> 6) & 127, off = lin & 63;
    gl2lds16(nb + (size_t)(1 + m0 + r) * 128 + hf * 64 + off, cQ + lin);
  }

  f32x4 zero4 = {0.f, 0.f, 0.f, 0.f};
  f32x4 oacc[2][4];
  f32x4 dacc[2];
#pragma unroll
  for (int i = 0; i < 2; ++i) {
    dacc[i] = zero4;
#pragma unroll
    for (int j = 0; j < 4; ++j) oacc[i][j] = zero4;
  }
  short8 ones;
#pragma unroll
  for (int i = 0; i < 8; ++i) ones[i] = (short)0x3F80;  // bf16 1.0

#pragma unroll 1
  for (int kt = 0; kt < 17; ++kt) {
    __syncthreads();
#pragma unroll
    for (int j = 0; j < 2; ++j) {
      int lin = (w << 11) + (j << 10) + (lane << 4);
      int hf = lin >> 12, r = (lin >> 6) & 63, off = lin & 63;
      gl2lds16(nb + (size_t)(kt * 64 + r) * 128 + hf * 64 + off, cK + lin);
      gl2lds16(tb + (size_t)r * (KPAD * 2) + kt * 128 + hf * 64 + off, cV + lin);
    }
    __syncthreads();

    // S^T = Kn_tile @ Qn^T  (C rows = keys, cols = queries) — cosine
    f32x4 sacc[4][2];
#pragma unroll
    for (int mt = 0; mt < 4; ++mt)
#pragma unroll
      for (int nt = 0; nt < 2; ++nt) sacc[mt][nt] = zero4;
#pragma unroll
    for (int kk = 0; kk < 2; ++kk) {
      short8 ak[4], bq[2];
#pragma unroll
      for (int mt = 0; mt < 4; ++mt)
        ak[mt] = *(const short8*)(cK + (kk << 12) + ((mt << 4) + lc) * 64 + (lr << 4));
#pragma unroll
      for (int nt = 0; nt < 2; ++nt)
        bq[nt] = *(const short8*)(cQ + (kk << 13) + ((w << 5) + (nt << 4) + lc) * 64 + (lr << 4));
#pragma unroll
      for (int mt = 0; mt < 4; ++mt)
#pragma unroll
        for (int nt = 0; nt < 2; ++nt)
          sacc[mt][nt] = __builtin_amdgcn_mfma_f32_16x16x32_bf16(ak[mt], bq[nt], sacc[mt][nt], 0, 0, 0);
    }

    // p = e^{0.125c} ~= 1 + 0.125c + 0.0078125c^2  (2 FMA/elem),
    // truncate-pack to bf16 via v_perm, b64 write into sP[q][k]
#pragma unroll
    for (int mt = 0; mt < 4; ++mt) {
      int kl0 = (mt << 4) + (lr << 2);
#pragma unroll
      for (int nt = 0; nt < 2; ++nt) {
        int q = (w << 5) + (nt << 4) + lc;
        float c0 = sacc[mt][nt][0], c1 = sacc[mt][nt][1];
        float c2 = sacc[mt][nt][2], c3 = sacc[mt][nt][3];
        float p0 = __builtin_fmaf(c0, __builtin_fmaf(c0, 0.0078125f, 0.125f), 1.0f);
        float p1 = __builtin_fmaf(c1, __builtin_fmaf(c1, 0.0078125f, 0.125f), 1.0f);
        float p2 = __builtin_fmaf(c2, __builtin_fmaf(c2, 0.0078125f, 0.125f), 1.0f);
        float p3 = __builtin_fmaf(c3, __builtin_fmaf(c3, 0.0078125f, 0.125f), 1.0f);
        uint2 pv;
        pv.x = __builtin_amdgcn_perm(__float_as_uint(p1), __float_as_uint(p0), 0x07060302u);
        pv.y = __builtin_amdgcn_perm(__float_as_uint(p3), __float_as_uint(p2), 0x07060302u);
        if (kt == 16) {  // keys 1024..1087: only key 1024 (kl0==0, elem 0) valid
          pv.x = (kl0 == 0) ? (pv.x & 0xFFFFu) : 0u;
          pv.y = 0u;
        }
        *(uint2*)(cP + q * 144 + (kl0 << 1)) = pv;
      }
    }

    // out += P @ V^T ; den += P @ ones   (sP rows are wave-private: no barrier)
#pragma unroll
    for (int kk = 0; kk < 2; ++kk) {
      short8 ap[2], bv[4];
#pragma unroll
      for (int mt = 0; mt < 2; ++mt)
        ap[mt] = *(const short8*)(cP + ((w << 5) + (mt << 4) + lc) * 144 + (kk << 6) + (lr << 4));
#pragma unroll
      for (int nt = 0; nt < 4; ++nt)
        bv[nt] = *(const short8*)(cV + (kk << 12) + ((nt << 4) + lc) * 64 + (lr << 4));
#pragma unroll
      for (int mt = 0; mt < 2; ++mt) {
#pragma unroll
        for (int nt = 0; nt < 4; ++nt)
          oacc[mt][nt] = __builtin_amdgcn_mfma_f32_16x16x32_bf16(ap[mt], bv[nt], oacc[mt][nt], 0, 0, 0);
        dacc[mt] = __builtin_amdgcn_mfma_f32_16x16x32_bf16(ap[mt], ones, dacc[mt], 0, 0, 0);
      }
    }
  }

  // epilogue: out/den -> attn rows 1+m0+q
#pragma unroll
  for (int mt = 0; mt < 2; ++mt) {
#pragma unroll
    for (int r = 0; r < 4; ++r) {
      int q = (w << 5) + (mt << 4) + (lr << 2) + r;
      int nseq = 1 + m0 + q;
      float rdn = 1.0f / dacc[mt][r];
      size_t obase = ((size_t)b * NSEQ + nseq) * DD + h * 64 + lc;
#pragma unroll
      for (int nt = 0; nt < 4; ++nt) attn[obase + (nt << 4)] = f2bf(oacc[mt][nt][r] * rdn);
    }
  }
}

// ---------------------------------------------------------------------------
// launcher
// ---------------------------------------------------------------------------
extern "C" void kernel_launch(void* const* d_in, const int* in_sizes, int n_in,
                              void* d_out, int out_size, void* d_ws, size_t ws_size,
                              hipStream_t stream) {
  const float* x      = (const float*)d_in[0];
  const float* w_qkv  = (const float*)d_in[1];
  const float* w_proj = (const float*)d_in[2];
  const float* b_proj = (const float*)d_in[3];
  float* out = (float*)d_out;
  char* ws = (char*)d_ws;

  // workspace layout (bytes). xb region is reused by vT after the qkv GEMM.
  u16*   xb   = (u16*)(ws + 0);            // 8320*768*2   = 12,779,520
  u16*   vT   = (u16*)(ws + 0);            // 96*64*1088*2 = 13,369,344 (reuses xb, done)
  u16*   wkv  = (u16*)(ws + 13369344);     // 1536*768*2   =  2,359,296
  u16*   wpj  = (u16*)(ws + 15728640);     // 768*768*2    =  1,179,648
  u16*   kvb  = (u16*)(ws + 16908288);     // 8320*1536*2  = 25,559,040
  float* q0   = (float*)(ws + 42467328);   // 8*768*4      =     24,576
  u16*   attn = (u16*)(ws + 42491904);     // 8320*768*2   = 12,779,520
  u16*   vn   = (u16*)(ws + 55271424);     // 96*1088*64*2 = 13,369,344
  // total: 68,640,768 bytes

  prep<<<8064, 256, 0, stream>>>(x, w_qkv, w_proj, xb, wkv, wpj, q0);
  gemm_bt<0, 12><<<864, 256, 0, stream>>>(xb, wkv, kvb, nullptr, nullptr, 1536);
  transpose_v<<<1632, 256, 0, stream>>>(kvb, vT, vn);     // overwrites xb/wkv region
  vv_attn<<<dim3(96, 9), 256, 0, stream>>>(vn, vT, attn, q0, kvb);
  gemm_bt<1, 6><<<432, 256, 0, stream>>>(attn, wpj, nullptr, out, b_proj, 768);
}